// Round 1
// baseline (9332.227 us; speedup 1.0000x reference)
//
#include <hip/hip_runtime.h>
#include <hip/hip_bf16.h>
#include <stdint.h>

#define B_  256
#define DIN 128
#define H_  256
#define T_  512
#define F_  64
#define ZW  1024   // 4*H

#define WGPC 16    // workgroups per cluster (h-col slices)
#define NWG  256   // 16 clusters x 16 slices
#define NTHR 256   // 4 waves

typedef __attribute__((ext_vector_type(8))) short bf16x8;
typedef __attribute__((ext_vector_type(4))) float f32x4;

__device__ __forceinline__ unsigned short f2bf(float f){
  uint32_t u = __float_as_uint(f);
  uint32_t r = (u + 0x7fffu + ((u >> 16) & 1u)) >> 16;   // RNE
  return (unsigned short)r;
}
__device__ __forceinline__ float sig(float x){ return 1.0f / (1.0f + __expf(-x)); }

// B-fragment gather from f32 weight matrix (row-major [K][ld]), bf16-converted.
// mfma_f32_16x16x32_bf16 B layout: col = lane&15, k = kbase + (lane>>4)*8 + j (contiguous k).
__device__ __forceinline__ bf16x8 load_wfrag(const float* W, int ld, int col, int kbase, int lane){
  int k0 = kbase + ((lane >> 4) << 3);
  int n  = col + (lane & 15);
  bf16x8 r;
#pragma unroll
  for(int j = 0; j < 8; ++j)
    r[j] = (short)f2bf(W[(size_t)(k0 + j) * ld + n]);
  return r;
}

__global__ __launch_bounds__(NTHR, 1)
void lstm_fused(const float* __restrict__ in,  const float* __restrict__ W_in, const float* __restrict__ b_in,
                const float* __restrict__ Wx1, const float* __restrict__ Wh1,  const float* __restrict__ b1,
                const float* __restrict__ Wx2, const float* __restrict__ Wh2,  const float* __restrict__ b2,
                const float* __restrict__ W_out, const float* __restrict__ b_out,
                float* __restrict__ out,
                uint32_t* __restrict__ cnt, uint32_t* __restrict__ h1buf, uint32_t* __restrict__ h2buf)
{
  const int tid  = threadIdx.x;
  const int lane = tid & 63;
  const int wv   = tid >> 6;          // wave 0..3 == gate id (and F-col block for out)
  const int wg   = blockIdx.x;
  const int cid  = wg >> 4;           // cluster = batch tile of 16 rows
  const int w16  = wg & 15;           // h-col slice within cluster
  const int rb   = cid * 16;          // batch row base
  const int jc   = w16 * 16;          // h-col base

  __shared__ float ins[16][DIN];          // 8 KB   (prologue)
  __shared__ float xs[16][H_];            // 16 KB  (prologue)
  __shared__ float zx1s[4][16][16];       // 4 KB   (constant over time)
  __shared__ float z1s[4][16][16];        // 4 KB
  __shared__ float z2s[4][16][16];        // 4 KB
  __shared__ float c1s[16][16];           // 1 KB
  __shared__ float c2s[16][16];           // 1 KB
  __shared__ float b2s[4][16];
  __shared__ unsigned short h1s[16][264]; // 8.25 KB, +8 pad breaks bank conflicts
  __shared__ unsigned short h2s[16][264];

  // ---------------- prologue ----------------
  for(int idx = tid; idx < 16 * DIN; idx += NTHR){
    int r = idx >> 7, k = idx & 127;
    ins[r][k] = in[(rb + r) * DIN + k];
  }
  if(tid < 64){
    int g = tid >> 4, j = tid & 15;
    b2s[g][j] = b2[g * H_ + jc + j];
  }
  { int r = tid >> 4, j = tid & 15; c1s[r][j] = 0.f; c2s[r][j] = 0.f; }
  __syncthreads();

  // x = relu(in @ W_in + b_in), f32 exact, per-cluster redundant (deterministic)
  { int r = tid >> 4, j = tid & 15;
    for(int cc = 0; cc < 16; ++cc){
      int c = j + 16 * cc;
      float acc = b_in[c];
      for(int k = 0; k < DIN; ++k) acc = fmaf(ins[r][k], W_in[k * H_ + c], acc);
      xs[r][c] = fmaxf(acc, 0.f);
    }
  }
  __syncthreads();

  // zx1 slice (constant across time): zx1[g][r][j] = x[r,:] @ Wx1[:, g*256+jc+j] + b1
  { int r = tid >> 4, j = tid & 15;
    for(int g = 0; g < 4; ++g){
      int c = g * H_ + jc + j;
      float acc = b1[c];
      for(int k = 0; k < H_; ++k) acc = fmaf(xs[r][k], Wx1[k * ZW + c], acc);
      zx1s[g][r][j] = acc;
    }
  }

  // Persistent weight fragments in registers (~128 VGPR/lane). One-time gather.
  const int nz = wv * H_ + jc;        // z-col base of this wave's gate tile
  bf16x8 bw1[8], bx2[8], bh2[8], bwo[8];
#pragma unroll
  for(int k8 = 0; k8 < 8; ++k8){
    bw1[k8] = load_wfrag(Wh1,  ZW, nz,      32 * k8, lane);
    bx2[k8] = load_wfrag(Wx2,  ZW, nz,      32 * k8, lane);
    bh2[k8] = load_wfrag(Wh2,  ZW, nz,      32 * k8, lane);
    bwo[k8] = load_wfrag(W_out, F_, wv * 16, 32 * k8, lane);
  }
  const float bo = b_out[wv * 16 + (lane & 15)];
  __syncthreads();

  const int arow = (lane >> 4) * 4;   // C/D: row = (lane>>4)*4 + reg  (verified m89)
  const int acol = lane & 15;         //      col = lane & 15
  const int uH2  = B_ * H_ / 2;       // u32 elems per ping-pong buffer

  // ---------------- 514 pipelined phases ----------------
  // phase p: h1(p) [p<T]; h2(p-1) [1<=p<=T]; out(p-2)=h2(p-2)@W_out [p>=2]
  for(int p = 0; p < T_ + 2; ++p){
    const uint32_t* h1rd = h1buf + (size_t)((p - 1) & 1) * uH2;  // h1(p-1)
    const uint32_t* h2rd = h2buf + (size_t)((p - 2) & 1) * uH2;  // h2(p-2)

    // cooperative coherent stage: 16 KB (h1,h2 tiles) -> LDS
    { int r = tid >> 4, k0 = (tid & 15) * 16;                    // 16 bf16 = 8 u32 each
      const uint32_t* s1 = h1rd + (((rb + r) * H_ + k0) >> 1);
      const uint32_t* s2 = h2rd + (((rb + r) * H_ + k0) >> 1);
      uint32_t* d1 = (uint32_t*)&h1s[r][k0];
      uint32_t* d2 = (uint32_t*)&h2s[r][k0];
#pragma unroll
      for(int j = 0; j < 8; ++j) d1[j] = __hip_atomic_load(s1 + j, __ATOMIC_RELAXED, __HIP_MEMORY_SCOPE_AGENT);
#pragma unroll
      for(int j = 0; j < 8; ++j) d2[j] = __hip_atomic_load(s2 + j, __ATOMIC_RELAXED, __HIP_MEMORY_SCOPE_AGENT);
    }
    __syncthreads();

    // A fragments from LDS: row = lane&15, k contiguous (m92/m97-verified layout)
    bf16x8 ah1[8], ah2[8];
#pragma unroll
    for(int k8 = 0; k8 < 8; ++k8){
      int k0 = 32 * k8 + ((lane >> 4) << 3);
      ah1[k8] = *(const bf16x8*)&h1s[lane & 15][k0];
      ah2[k8] = *(const bf16x8*)&h2s[lane & 15][k0];
    }

    f32x4 z1a = {0.f,0.f,0.f,0.f}, z2a = {0.f,0.f,0.f,0.f}, oa = {0.f,0.f,0.f,0.f};
#pragma unroll
    for(int k8 = 0; k8 < 8; ++k8) z1a = __builtin_amdgcn_mfma_f32_16x16x32_bf16(ah1[k8], bw1[k8], z1a, 0, 0, 0);
#pragma unroll
    for(int k8 = 0; k8 < 8; ++k8) z2a = __builtin_amdgcn_mfma_f32_16x16x32_bf16(ah1[k8], bx2[k8], z2a, 0, 0, 0);
#pragma unroll
    for(int k8 = 0; k8 < 8; ++k8) z2a = __builtin_amdgcn_mfma_f32_16x16x32_bf16(ah2[k8], bh2[k8], z2a, 0, 0, 0);
#pragma unroll
    for(int k8 = 0; k8 < 8; ++k8) oa  = __builtin_amdgcn_mfma_f32_16x16x32_bf16(ah2[k8], bwo[k8], oa, 0, 0, 0);

    // fused head: out[:, p-2, :] = h2(p-2) @ W_out + b_out
    if(p >= 2){
      const int tout = p - 2;
#pragma unroll
      for(int reg = 0; reg < 4; ++reg)
        out[((size_t)(rb + arow + reg) * T_ + tout) * F_ + wv * 16 + acol] = oa[reg] + bo;
    }

    if(p < T_){
#pragma unroll
      for(int reg = 0; reg < 4; ++reg) z1s[wv][arow + reg][acol] = z1a[reg];
    }
    if(p >= 1 && p <= T_){
#pragma unroll
      for(int reg = 0; reg < 4; ++reg) z2s[wv][arow + reg][acol] = z2a[reg];
    }
    __syncthreads();

    // gate combine + coherent publish (ping-pong)
    { int r = tid >> 4, j = tid & 15;
      if(p < T_){
        float iv = zx1s[0][r][j] + z1s[0][r][j];
        float fv = zx1s[1][r][j] + z1s[1][r][j];
        float gv = zx1s[2][r][j] + z1s[2][r][j];
        float ov = zx1s[3][r][j] + z1s[3][r][j];
        float cn = sig(fv) * c1s[r][j] + sig(iv) * tanhf(gv);
        float hn = sig(ov) * tanhf(cn);
        c1s[r][j] = cn;
        uint32_t mine = f2bf(hn);
        uint32_t part = (uint32_t)__shfl_xor((int)mine, 1, 64);
        if((j & 1) == 0){
          uint32_t pk = (mine & 0xffffu) | (part << 16);
          uint32_t* dst = h1buf + (size_t)(p & 1) * uH2 + (((rb + r) * H_ + jc + j) >> 1);
          __hip_atomic_store(dst, pk, __ATOMIC_RELAXED, __HIP_MEMORY_SCOPE_AGENT);
        }
      }
      if(p >= 1 && p <= T_){
        float iv = z2s[0][r][j] + b2s[0][j];
        float fv = z2s[1][r][j] + b2s[1][j];
        float gv = z2s[2][r][j] + b2s[2][j];
        float ov = z2s[3][r][j] + b2s[3][j];
        float cn = sig(fv) * c2s[r][j] + sig(iv) * tanhf(gv);
        float hn = sig(ov) * tanhf(cn);
        c2s[r][j] = cn;
        uint32_t mine = f2bf(hn);
        uint32_t part = (uint32_t)__shfl_xor((int)mine, 1, 64);
        if((j & 1) == 0){
          uint32_t pk = (mine & 0xffffu) | (part << 16);
          uint32_t* dst = h2buf + (size_t)((p - 1) & 1) * uH2 + (((rb + r) * H_ + jc + j) >> 1);
          __hip_atomic_store(dst, pk, __ATOMIC_RELAXED, __HIP_MEMORY_SCOPE_AGENT);
        }
      }
    }
    __syncthreads();   // all stores issued (drained at barrier) before arrival

    // per-cluster (16-wg) barrier, monotonic counter, release/acquire at agent scope
    if(p < T_ + 1){
      if(tid == 0){
        __hip_atomic_fetch_add(&cnt[cid], 1u, __ATOMIC_RELEASE, __HIP_MEMORY_SCOPE_AGENT);
        const uint32_t tgt = (uint32_t)(p + 1) * WGPC;
        while(__hip_atomic_load(&cnt[cid], __ATOMIC_ACQUIRE, __HIP_MEMORY_SCOPE_AGENT) < tgt){
          __builtin_amdgcn_s_sleep(2);
        }
      }
      __syncthreads();
    }
  }
}

extern "C" void kernel_launch(void* const* d_in, const int* in_sizes, int n_in,
                              void* d_out, int out_size, void* d_ws, size_t ws_size,
                              hipStream_t stream)
{
  const float* in    = (const float*)d_in[0];
  const float* W_in  = (const float*)d_in[1];
  const float* b_in  = (const float*)d_in[2];
  const float* Wx1   = (const float*)d_in[3];
  const float* Wh1   = (const float*)d_in[4];
  const float* b1    = (const float*)d_in[5];
  const float* Wx2   = (const float*)d_in[6];
  const float* Wh2   = (const float*)d_in[7];
  const float* b2    = (const float*)d_in[8];
  const float* W_out = (const float*)d_in[9];
  const float* b_out = (const float*)d_in[10];
  float* out = (float*)d_out;

  uint8_t* ws = (uint8_t*)d_ws;
  uint32_t* cnt   = (uint32_t*)ws;                        // 256 B (16 counters)
  uint32_t* h1buf = (uint32_t*)(ws + 256);                // [2][256][256] bf16 = 256 KB
  uint32_t* h2buf = (uint32_t*)(ws + 256 + 2 * B_ * H_ * 2);
  const size_t need = 256 + 2 * (size_t)(2 * B_ * H_ * 2);
  (void)in_sizes; (void)n_in; (void)out_size; (void)ws_size;

  hipMemsetAsync(d_ws, 0, need, stream);                  // zero counters + h ping-pong bufs
  hipLaunchKernelGGL(lstm_fused, dim3(NWG), dim3(NTHR), 0, stream,
                     in, W_in, b_in, Wx1, Wh1, b1, Wx2, Wh2, b2, W_out, b_out,
                     out, cnt, h1buf, h2buf);
}

// Round 3
// 7689.977 us; speedup vs baseline: 1.2136x; 1.2136x over previous
//
#include <hip/hip_runtime.h>
#include <hip/hip_bf16.h>
#include <stdint.h>

#define B_  256
#define DIN 128
#define H_  256
#define T_  512
#define F_  64
#define ZW  1024   // 4*H

#define WGPC 16    // workgroups per cluster (h-col slices)
#define NWG  256   // 16 clusters x 16 wgs
#define NTHR 256   // 4 waves
#define CNTSTRIDE 64  // u32s: 256B between cluster counters (false-sharing fix)

typedef __attribute__((ext_vector_type(8))) short bf16x8;
typedef __attribute__((ext_vector_type(4))) float f32x4;

__device__ __forceinline__ unsigned short f2bf(float f){
  uint32_t u = __float_as_uint(f);
  uint32_t r = (u + 0x7fffu + ((u >> 16) & 1u)) >> 16;   // RNE
  return (unsigned short)r;
}
__device__ __forceinline__ float sig(float x){ return 1.0f / (1.0f + __expf(-x)); }
// branchless fast tanh: t=e^{-2|x|} in (0,1], no overflow
__device__ __forceinline__ float tanh_fast(float x){
  float t = __expf(-2.0f * fabsf(x));
  return copysignf((1.0f - t) / (1.0f + t), x);
}

// B-fragment gather from f32 weight matrix (row-major [K][ld]), bf16-converted.
// mfma_f32_16x16x32_bf16 B layout: col = lane&15, k = kbase + (lane>>4)*8 + j.
__device__ __forceinline__ bf16x8 load_wfrag(const float* W, int ld, int col, int kbase, int lane){
  int k0 = kbase + ((lane >> 4) << 3);
  int n  = col + (lane & 15);
  bf16x8 r;
#pragma unroll
  for(int j = 0; j < 8; ++j)
    r[j] = (short)f2bf(W[(size_t)(k0 + j) * ld + n]);
  return r;
}

__global__ __launch_bounds__(NTHR, 1)
void lstm_fused(const float* __restrict__ in,  const float* __restrict__ W_in, const float* __restrict__ b_in,
                const float* __restrict__ Wx1, const float* __restrict__ Wh1,  const float* __restrict__ b1,
                const float* __restrict__ Wx2, const float* __restrict__ Wh2,  const float* __restrict__ b2,
                const float* __restrict__ W_out, const float* __restrict__ b_out,
                float* __restrict__ out,
                uint32_t* __restrict__ cnt, uint32_t* __restrict__ h1buf, uint32_t* __restrict__ h2buf)
{
  const int tid  = threadIdx.x;
  const int lane = tid & 63;
  const int wv   = tid >> 6;          // wave 0..3 == gate id (and F-col block for head)
  const int wg   = blockIdx.x;
  const int cid  = wg >> 4;           // cluster = batch tile of 16 rows
  const int w16  = wg & 15;           // h-col slice within cluster
  const int rb   = cid * 16;          // batch row base
  const int jc   = w16 * 16;          // h-col base

  __shared__ float ins[16][DIN];          // prologue
  __shared__ float xs[16][H_];            // prologue
  __shared__ float zx1s[4][16][16];       // constant over time
  __shared__ float z1s[4][16][16];
  __shared__ float z2s[4][16][16];
  __shared__ float c1s[16][16];
  __shared__ float c2s[16][16];
  __shared__ float b2s[4][16];
  __shared__ unsigned short h1s[16][264]; // +8 pad
  __shared__ unsigned short h2s[16][264];

  // ---------------- prologue ----------------
  for(int idx = tid; idx < 16 * DIN; idx += NTHR){
    int r = idx >> 7, k = idx & 127;
    ins[r][k] = in[(rb + r) * DIN + k];
  }
  if(tid < 64){
    int g = tid >> 4, j = tid & 15;
    b2s[g][j] = b2[g * H_ + jc + j];
  }
  { int r = tid >> 4, j = tid & 15; c1s[r][j] = 0.f; c2s[r][j] = 0.f; }
  __syncthreads();

  // x = relu(in @ W_in + b_in), f32 exact, per-cluster redundant (deterministic)
  { int r = tid >> 4, j = tid & 15;
    for(int cc = 0; cc < 16; ++cc){
      int c = j + 16 * cc;
      float acc = b_in[c];
      for(int k = 0; k < DIN; ++k) acc = fmaf(ins[r][k], W_in[k * H_ + c], acc);
      xs[r][c] = fmaxf(acc, 0.f);
    }
  }
  __syncthreads();

  // zx1 slice (constant across time)
  { int r = tid >> 4, j = tid & 15;
    for(int g = 0; g < 4; ++g){
      int c = g * H_ + jc + j;
      float acc = b1[c];
      for(int k = 0; k < H_; ++k) acc = fmaf(xs[r][k], Wx1[k * ZW + c], acc);
      zx1s[g][r][j] = acc;
    }
  }

  // Persistent weight fragments (~128 VGPR/lane), one-time gather.
  const int nz = wv * H_ + jc;
  bf16x8 bw1[8], bx2[8], bh2[8], bwo[8];
#pragma unroll
  for(int k8 = 0; k8 < 8; ++k8){
    bw1[k8] = load_wfrag(Wh1,  ZW, nz,      32 * k8, lane);
    bx2[k8] = load_wfrag(Wx2,  ZW, nz,      32 * k8, lane);
    bh2[k8] = load_wfrag(Wh2,  ZW, nz,      32 * k8, lane);
    bwo[k8] = load_wfrag(W_out, F_, wv * 16, 32 * k8, lane);
  }
  const float bo = b_out[wv * 16 + (lane & 15)];
  __syncthreads();

  const int arow = (lane >> 4) * 4;   // C/D: row = (lane>>4)*4 + reg (m89)
  const int acol = lane & 15;
  const int uH2  = B_ * H_ / 2;       // u32 elems per ping-pong slot
  uint32_t* const mycnt = cnt + ((uint32_t)cid << 6);

  // ---------------- 514 pipelined phases ----------------
  // phase p: h1(p) [p<T]; h2(p-1) [1<=p<=T]; out(p-2)=h2(p-2)@W_out [p>=2]
  for(int p = 0; p < T_ + 2; ++p){
    const uint64_t* h1rd = (const uint64_t*)(h1buf + (size_t)((p - 1) & 1) * uH2);
    const uint64_t* h2rd = (const uint64_t*)(h2buf + (size_t)((p - 2) & 1) * uH2);

    // (1) cooperative coherent stage: 16 KB (h1,h2 tiles) -> LDS, u64 atomic loads
    { int r = tid >> 4, k0 = (tid & 15) * 16;                   // 16 bf16 = 4 u64 each
      const uint64_t* s1 = h1rd + (((rb + r) * H_ + k0) >> 2);
      const uint64_t* s2 = h2rd + (((rb + r) * H_ + k0) >> 2);
      uint64_t* d1 = (uint64_t*)&h1s[r][k0];
      uint64_t* d2 = (uint64_t*)&h2s[r][k0];
#pragma unroll
      for(int j = 0; j < 4; ++j) d1[j] = __hip_atomic_load(s1 + j, __ATOMIC_RELAXED, __HIP_MEMORY_SCOPE_AGENT);
#pragma unroll
      for(int j = 0; j < 4; ++j) d2[j] = __hip_atomic_load(s2 + j, __ATOMIC_RELAXED, __HIP_MEMORY_SCOPE_AGENT);
    }
    __syncthreads();

    // A fragments from LDS
    bf16x8 ah1[8], ah2[8];
#pragma unroll
    for(int k8 = 0; k8 < 8; ++k8){
      int k0 = 32 * k8 + ((lane >> 4) << 3);
      ah1[k8] = *(const bf16x8*)&h1s[lane & 15][k0];
      ah2[k8] = *(const bf16x8*)&h2s[lane & 15][k0];
    }

    f32x4 z1a = {0.f,0.f,0.f,0.f}, z2a = {0.f,0.f,0.f,0.f};
#pragma unroll
    for(int k8 = 0; k8 < 8; ++k8) z1a = __builtin_amdgcn_mfma_f32_16x16x32_bf16(ah1[k8], bw1[k8], z1a, 0, 0, 0);
#pragma unroll
    for(int k8 = 0; k8 < 8; ++k8) z2a = __builtin_amdgcn_mfma_f32_16x16x32_bf16(ah1[k8], bx2[k8], z2a, 0, 0, 0);
#pragma unroll
    for(int k8 = 0; k8 < 8; ++k8) z2a = __builtin_amdgcn_mfma_f32_16x16x32_bf16(ah2[k8], bh2[k8], z2a, 0, 0, 0);

    if(p < T_){
#pragma unroll
      for(int reg = 0; reg < 4; ++reg) z1s[wv][arow + reg][acol] = z1a[reg];
    }
    if(p >= 1 && p <= T_){
#pragma unroll
      for(int reg = 0; reg < 4; ++reg) z2s[wv][arow + reg][acol] = z2a[reg];
    }
    __syncthreads();   // (2)

    // gate combine + coherent publish (ping-pong)
    { int r = tid >> 4, j = tid & 15;
      if(p < T_){
        float iv = zx1s[0][r][j] + z1s[0][r][j];
        float fv = zx1s[1][r][j] + z1s[1][r][j];
        float gv = zx1s[2][r][j] + z1s[2][r][j];
        float ov = zx1s[3][r][j] + z1s[3][r][j];
        float cn = sig(fv) * c1s[r][j] + sig(iv) * tanh_fast(gv);
        float hn = sig(ov) * tanh_fast(cn);
        c1s[r][j] = cn;
        uint32_t mine = f2bf(hn);
        uint32_t part = (uint32_t)__shfl_xor((int)mine, 1, 64);
        if((j & 1) == 0){
          uint32_t pk = (mine & 0xffffu) | (part << 16);
          uint32_t* dst = h1buf + (size_t)(p & 1) * uH2 + (((rb + r) * H_ + jc + j) >> 1);
          __hip_atomic_store(dst, pk, __ATOMIC_RELAXED, __HIP_MEMORY_SCOPE_AGENT);
        }
      }
      if(p >= 1 && p <= T_){
        float iv = z2s[0][r][j] + b2s[0][j];
        float fv = z2s[1][r][j] + b2s[1][j];
        float gv = z2s[2][r][j] + b2s[2][j];
        float ov = z2s[3][r][j] + b2s[3][j];
        float cn = sig(fv) * c2s[r][j] + sig(iv) * tanh_fast(gv);
        float hn = sig(ov) * tanh_fast(cn);
        c2s[r][j] = cn;
        uint32_t mine = f2bf(hn);
        uint32_t part = (uint32_t)__shfl_xor((int)mine, 1, 64);
        if((j & 1) == 0){
          uint32_t pk = (mine & 0xffffu) | (part << 16);
          uint32_t* dst = h2buf + (size_t)((p - 1) & 1) * uH2 + (((rb + r) * H_ + jc + j) >> 1);
          __hip_atomic_store(dst, pk, __ATOMIC_RELAXED, __HIP_MEMORY_SCOPE_AGENT);
        }
      }
    }
    __syncthreads();   // (3) drains publish stores before the counter add

    if(p < T_ + 1){
      if(tid == 0)
        __hip_atomic_fetch_add(mycnt, 1u, __ATOMIC_RELEASE, __HIP_MEMORY_SCOPE_AGENT);

      // head GEMM overlapped with barrier propagation: out(p-2) = h2(p-2) @ W_out
      if(p >= 2){
        f32x4 oa = {0.f,0.f,0.f,0.f};
#pragma unroll
        for(int k8 = 0; k8 < 8; ++k8) oa = __builtin_amdgcn_mfma_f32_16x16x32_bf16(ah2[k8], bwo[k8], oa, 0, 0, 0);
        const int tout = p - 2;
#pragma unroll
        for(int reg = 0; reg < 4; ++reg)
          out[((size_t)(rb + arow + reg) * T_ + tout) * F_ + wv * 16 + acol] = oa[reg] + bo;
      }

      // all-threads spin (relaxed poll, acquire confirm). Uniform per wave.
      const uint32_t tgt = (uint32_t)(p + 1) * WGPC;
      while(__hip_atomic_load(mycnt, __ATOMIC_RELAXED, __HIP_MEMORY_SCOPE_AGENT) < tgt){
        __builtin_amdgcn_s_sleep(2);
      }
      (void)__hip_atomic_load(mycnt, __ATOMIC_ACQUIRE, __HIP_MEMORY_SCOPE_AGENT);
    } else {
      // final phase: just the last head tile
      f32x4 oa = {0.f,0.f,0.f,0.f};
#pragma unroll
      for(int k8 = 0; k8 < 8; ++k8) oa = __builtin_amdgcn_mfma_f32_16x16x32_bf16(ah2[k8], bwo[k8], oa, 0, 0, 0);
      const int tout = p - 2;
#pragma unroll
      for(int reg = 0; reg < 4; ++reg)
        out[((size_t)(rb + arow + reg) * T_ + tout) * F_ + wv * 16 + acol] = oa[reg] + bo;
    }
  }
}

extern "C" void kernel_launch(void* const* d_in, const int* in_sizes, int n_in,
                              void* d_out, int out_size, void* d_ws, size_t ws_size,
                              hipStream_t stream)
{
  const float* in    = (const float*)d_in[0];
  const float* W_in  = (const float*)d_in[1];
  const float* b_in  = (const float*)d_in[2];
  const float* Wx1   = (const float*)d_in[3];
  const float* Wh1   = (const float*)d_in[4];
  const float* b1    = (const float*)d_in[5];
  const float* Wx2   = (const float*)d_in[6];
  const float* Wh2   = (const float*)d_in[7];
  const float* b2    = (const float*)d_in[8];
  const float* W_out = (const float*)d_in[9];
  const float* b_out = (const float*)d_in[10];
  float* out = (float*)d_out;

  uint8_t* ws = (uint8_t*)d_ws;
  uint32_t* cnt   = (uint32_t*)ws;                         // 16 counters @ 256B stride = 4 KB
  uint32_t* h1buf = (uint32_t*)(ws + 4096);                // [2][256][256] bf16 = 256 KB
  uint32_t* h2buf = (uint32_t*)(ws + 4096 + 2 * B_ * H_ * 2);
  const size_t need = 4096 + 2 * (size_t)(2 * B_ * H_ * 2);
  (void)in_sizes; (void)n_in; (void)out_size; (void)ws_size;

  hipMemsetAsync(d_ws, 0, need, stream);                   // zero counters + ping-pong bufs
  hipLaunchKernelGGL(lstm_fused, dim3(NWG), dim3(NTHR), 0, stream,
                     in, W_in, b_in, Wx1, Wh1, b1, Wx2, Wh2, b2, W_out, b_out,
                     out, cnt, h1buf, h2buf);
}